// Round 16
// baseline (703.676 us; speedup 1.0000x reference)
//
#include <hip/hip_runtime.h>
#include <math.h>

// ---------------------------------------------------------------------------
// LocalSlidingWindow_DisentangledAttention — Round 16:
//  R15 base + T14 async-stage splits in attn:
//   - Q fragments loaded direct from global (Q LDS region freed)
//   - full posk staged in phase 0 (second half in dead T/Q region) ->
//     phase 1 is one 24-tile loop, 2 barriers removed
//   - K/PQ global loads issued before phase-2 gather (latency hidden),
//     ds_writes after C2P death barrier
//   - Vt global loads issued before phase-5 MFMA, writes after
//   - pre/post-phase-5 barriers removed (disjoint-region proof in comments)
// Workspace = 207,618,048 B (proven).
// ---------------------------------------------------------------------------

#define NHEADS 12
#define HDIM   64
#define SEQ    8192
#define HID    768
#define BSZ    128
#define WIN    384
#define PBUCK  512

typedef __attribute__((ext_vector_type(8))) short bf16x8;
typedef __attribute__((ext_vector_type(4))) float f32x4;
#define MFMA16(a, b, c) __builtin_amdgcn_mfma_f32_16x16x32_bf16((a), (b), (c), 0, 0, 0)

// attn LDS byte map (dynamic, 156288 total)
#define C2PS    396      // C2P row stride (ushorts)
#define TLS     186      // Tl row stride (ushorts)
#define C2P_OFF 0        // [128][396] bf16 = 101376   (phase 1-2)
#define K_OFF   0        // [384][64]  bf16 = 49152    (phase 3+)
#define PQ_OFF  49152    // [384][64]  bf16 = 49152    (phase 4)
#define VT_OFF  49152    // [64][384]  bf16 = 49152    (PV phase)
#define T_OFF   101376   // Tl slot0 [32][186] = 11904 (phase 4)
#define PK2_OFF 101376   // posk[192:384] [192][64] = 24576 (phase 0-1)
#define Q_OFF   113280   // Tl slot1 region (phase 4); posk2 tail (phase 0-1)
#define PKH_OFF 129664   // [192][64]  bf16 = 24576   (phase 0-1)
#define LUT_OFF 154240   // [511] int  = 2044
#define SMEM_ATTN 156288

// out_ln LDS byte map (dynamic, 71168)
#define OL_AU 0          // [64][40] bf16 = 5120
#define OL_BU 5120       // [768][40] bf16 = 61440
#define OL_R1 66560      // [64][8] f32 = 2048
#define OL_R2 68608      // [64][8] f32 = 2048
#define OL_MU 70656      // [64] f32
#define OL_RS 70912      // [64] f32
#define SMEM_OL 71168

typedef __attribute__((address_space(3))) unsigned int lds_uint;
typedef const __attribute__((address_space(1))) unsigned int glob_uint;

__device__ __forceinline__ unsigned short f2bf(float f) {
  unsigned int x = __builtin_bit_cast(unsigned int, f);
  unsigned int r = (x + 0x7FFFu + ((x >> 16) & 1u)) >> 16;
  return (unsigned short)r;
}
__device__ __forceinline__ float bf2f(unsigned short u) {
  unsigned int x = ((unsigned int)u) << 16;
  return __builtin_bit_cast(float, x);
}

// idx(rel) for rel in [-383, 127]
__device__ __forceinline__ int bucket_idx(int rel) {
  if (rel >= -128) return rel + 256;
  float a = (float)(-rel);
  float t = logf(a * (1.0f / 128.0f));
  t = t / 0.6892332813f;
  t = t * 127.0f;
  int lp = (int)(ceilf(t) + 128.0f);
  int r = 256 - lp;
  return r < 0 ? 0 : r;
}

// ---- fragment-major layout helpers (attn) ----
__device__ __forceinline__ bf16x8 ldfrag128(const char* sm, int byteBase,
                                            int row, int rowBytes, int slice,
                                            int g) {
  const int swz = (row & 7) << 4;
  return *(const bf16x8*)(sm + byteBase + row * rowBytes +
                          (((slice << 6) + (g << 4)) ^ swz));
}
__device__ __forceinline__ void stfrag(char* base, int row, int rowBytes,
                                       int c, uint4 v) {
  const int swz = (row & 7) << 4;
  const int s = c >> 2, h = (c >> 1) & 1;
  const int n1 = s * 64 + ((2 * c) & 3) * 16 + h * 8;
  const int n2 = s * 64 + ((2 * c + 1) & 3) * 16 + h * 8;
  char* p = base + row * rowBytes;
  *(uint2*)(p + (n1 ^ swz)) = make_uint2(v.x, v.y);
  *(uint2*)(p + (n2 ^ swz)) = make_uint2(v.z, v.w);
}
__device__ __forceinline__ int vperm(int o) {
  return (o & ~31) + (((o >> 2) & 3) << 3) + (((o >> 4) & 1) << 2) + (o & 3);
}

// old-layout fragment read (qkv/out_ln: 2x8B pattern)
__device__ __forceinline__ bf16x8 ldfrag(const char* sm, int byteBase, int row,
                                         int rowBytes, int slice, int g) {
  const int swz = (row & 7) << 4;
  const char* p = sm + byteBase + row * rowBytes;
  union { bf16x8 v; uint2 u2[2]; } w;
  w.u2[0] = *(const uint2*)(p + (((slice << 6) + (g << 3)) ^ swz));
  w.u2[1] = *(const uint2*)(p + (((slice << 6) + 32 + (g << 3)) ^ swz));
  return w.v;
}

// Fragment from padded (40-ushort rows, no swizzle) LDS tile for out_ln.
__device__ __forceinline__ bf16x8 olfrag(const unsigned short* base, int row,
                                         int g) {
  const unsigned short* p = base + row * 40 + 4 * g;
  union { bf16x8 v; uint2 u2[2]; } w;
  w.u2[0] = *(const uint2*)(p);
  w.u2[1] = *(const uint2*)(p + 16);
  return w.v;
}

// ---------------------------------------------------------------------------
// hidden fp32 -> bf16
__global__ __launch_bounds__(256) void hbf_conv(const float* __restrict__ src,
                                                unsigned short* __restrict__ dst) {
  size_t i = ((size_t)blockIdx.x * 256 + threadIdx.x) * 8;
  float4 a = *(const float4*)(src + i);
  float4 b = *(const float4*)(src + i + 4);
  union { uint4 q; unsigned short u[8]; } w;
  w.u[0] = f2bf(a.x); w.u[1] = f2bf(a.y); w.u[2] = f2bf(a.z); w.u[3] = f2bf(a.w);
  w.u[4] = f2bf(b.x); w.u[5] = f2bf(b.y); w.u[6] = f2bf(b.z); w.u[7] = f2bf(b.w);
  *(uint4*)(dst + i) = w.q;
}

// Weight transpose fp32 -> bf16: Wt[z*768 + n][k] = W_z[k][n], z = 0..3
__global__ __launch_bounds__(256) void conv_wt(const float* __restrict__ W0,
                                               const float* __restrict__ W1,
                                               const float* __restrict__ W2,
                                               const float* __restrict__ W3,
                                               unsigned short* __restrict__ Wt) {
  __shared__ float tile[64][65];
  int bx = blockIdx.x, by = blockIdx.y, z = blockIdx.z;
  const float* W = (z == 0) ? W0 : (z == 1 ? W1 : (z == 2 ? W2 : W3));
  int t = threadIdx.x;
  int c = t & 63, r0 = (t >> 6) * 16;
#pragma unroll
  for (int rr = 0; rr < 16; ++rr)
    tile[r0 + rr][c] = W[(size_t)(by * 64 + r0 + rr) * HID + bx * 64 + c];
  __syncthreads();
#pragma unroll
  for (int rr = 0; rr < 16; ++rr) {
    int nw = r0 + rr;
    Wt[((size_t)z * HID + bx * 64 + nw) * HID + by * 64 + c] = f2bf(tile[c][nw]);
  }
}

// Positional projection (fp32 math) -> bf16 posq/posk [h][512][64]
__global__ __launch_bounds__(256) void pos_gemm(
    const float* __restrict__ relpos, const float* __restrict__ Wq,
    const float* __restrict__ Wk, const float* __restrict__ bq,
    const float* __restrict__ bk, unsigned short* __restrict__ posq,
    unsigned short* __restrict__ posk) {
  __shared__ float At[32][68];
  __shared__ float Bs[32][68];
  int m0 = blockIdx.x * 64;
  int n0 = blockIdx.y * 64;
  int w = n0 / HID;
  int nc0 = n0 % HID;
  const float* W = (w == 0) ? Wq : Wk;
  const float* bias = (w == 0) ? bq : bk;
  int t = threadIdx.x;
  int tx = t & 15, ty = t >> 4;
  float acc[4][4] = {};
  for (int k0 = 0; k0 < HID; k0 += 32) {
#pragma unroll
    for (int u = 0; u < 2; ++u) {
      int f = t * 2 + u;
      int r = f >> 3, c4 = f & 7;
      float4 av = *(const float4*)(relpos + (size_t)(m0 + r) * HID + k0 + c4 * 4);
      At[c4 * 4 + 0][r] = av.x; At[c4 * 4 + 1][r] = av.y;
      At[c4 * 4 + 2][r] = av.z; At[c4 * 4 + 3][r] = av.w;
    }
#pragma unroll
    for (int u = 0; u < 2; ++u) {
      int f = t * 2 + u;
      int kk = f >> 4, c4 = f & 15;
      float4 bv4 = *(const float4*)(W + (size_t)(k0 + kk) * HID + nc0 + c4 * 4);
      *(float4*)&Bs[kk][c4 * 4] = bv4;
    }
    __syncthreads();
#pragma unroll
    for (int kk = 0; kk < 32; ++kk) {
      float4 a4 = *(const float4*)&At[kk][ty * 4];
      float4 b4 = *(const float4*)&Bs[kk][tx * 4];
      float av[4] = {a4.x, a4.y, a4.z, a4.w};
      float bvv[4] = {b4.x, b4.y, b4.z, b4.w};
#pragma unroll
      for (int i = 0; i < 4; ++i)
#pragma unroll
        for (int jj = 0; jj < 4; ++jj) acc[i][jj] += av[i] * bvv[jj];
    }
    __syncthreads();
  }
  int h = nc0 >> 6;
  unsigned short* dst = (w == 0) ? posq : posk;
#pragma unroll
  for (int i = 0; i < 4; ++i) {
    int p = m0 + ty * 4 + i;
    ushort4 o;
    o.x = f2bf(acc[i][0] + bias[nc0 + tx * 4 + 0]);
    o.y = f2bf(acc[i][1] + bias[nc0 + tx * 4 + 1]);
    o.z = f2bf(acc[i][2] + bias[nc0 + tx * 4 + 2]);
    o.w = f2bf(acc[i][3] + bias[nc0 + tx * 4 + 3]);
    *(ushort4*)(dst + ((size_t)h * PBUCK + p) * HDIM + tx * 4) = o;
  }
}

// ---------------------------------------------------------------------------
// QKV projection, bf16 MFMA. Tile 128x128, BK=64, 256 thr = 4 waves (2x2).
// Staging via global_load_lds width-16 (pre-swizzled global source).
__global__ __launch_bounds__(256) void qkv_mfma(
    const unsigned short* __restrict__ hbf, const unsigned short* __restrict__ Wt,
    const float* __restrict__ bq, const float* __restrict__ bk,
    const float* __restrict__ bv, unsigned short* __restrict__ qws,
    unsigned short* __restrict__ kws, unsigned short* __restrict__ vws) {
  __shared__ unsigned short As[8192];
  __shared__ unsigned short Bs[8192];
  const int t = threadIdx.x;
  const int lane = t & 63;
  const int l15 = lane & 15, g = lane >> 4;
  const int wave = t >> 6;
  const int wy = wave >> 1, wx = wave & 1;
  const int bid = blockIdx.x;
  const int wg = (bid & 7) * 576 + (bid >> 3);
  const int n0 = (wg % 18) * 128;
  const int m0 = (wg / 18) * 128;

  const int rsub = lane >> 3;
  const int slot = lane & 7;

  f32x4 acc[4][4];
#pragma unroll
  for (int i = 0; i < 4; ++i)
#pragma unroll
    for (int j = 0; j < 4; ++j) acc[i][j] = (f32x4){0.f, 0.f, 0.f, 0.f};

  for (int k0 = 0; k0 < HID; k0 += 64) {
#pragma unroll
    for (int i = 0; i < 4; ++i) {
      int row = wave * 32 + i * 8 + rsub;
      int cx = slot ^ (row & 7);
      const unsigned short* src = hbf + (size_t)(m0 + row) * HID + k0 + cx * 8;
      __builtin_amdgcn_global_load_lds(
          (glob_uint*)src, (lds_uint*)((char*)As + wave * 4096 + i * 1024),
          16, 0, 0);
    }
#pragma unroll
    for (int i = 0; i < 4; ++i) {
      int row = wave * 32 + i * 8 + rsub;
      int cx = slot ^ (row & 7);
      const unsigned short* src = Wt + (size_t)(n0 + row) * HID + k0 + cx * 8;
      __builtin_amdgcn_global_load_lds(
          (glob_uint*)src, (lds_uint*)((char*)Bs + wave * 4096 + i * 1024),
          16, 0, 0);
    }
    __syncthreads();
    bf16x8 af[4][2], bf[4][2];
#pragma unroll
    for (int mt = 0; mt < 4; ++mt) {
      int row = wy * 64 + mt * 16 + l15;
#pragma unroll
      for (int s = 0; s < 2; ++s)
        af[mt][s] = ldfrag((const char*)As, 0, row, 128, s, g);
    }
#pragma unroll
    for (int nt = 0; nt < 4; ++nt) {
      int row = wx * 64 + nt * 16 + l15;
#pragma unroll
      for (int s = 0; s < 2; ++s)
        bf[nt][s] = ldfrag((const char*)Bs, 0, row, 128, s, g);
    }
#pragma unroll
    for (int mt = 0; mt < 4; ++mt)
#pragma unroll
      for (int nt = 0; nt < 4; ++nt) {
        acc[mt][nt] = MFMA16(af[mt][0], bf[nt][0], acc[mt][nt]);
        acc[mt][nt] = MFMA16(af[mt][1], bf[nt][1], acc[mt][nt]);
      }
    __syncthreads();
  }

  const int w = n0 / HID;  // 0:q 1:k 2:v
  const float* bias = (w == 0) ? bq : (w == 1 ? bk : bv);
  unsigned short* dst = (w == 0) ? qws : (w == 1 ? kws : vws);
#pragma unroll
  for (int nt = 0; nt < 4; ++nt) {
    int gn = n0 + wx * 64 + nt * 16 + l15;
    int nc = gn - w * HID;
    int h = nc >> 6, d = nc & 63;
    float bval = bias[nc];
#pragma unroll
    for (int mt = 0; mt < 4; ++mt) {
      f32x4 a = acc[mt][nt];
#pragma unroll
      for (int r = 0; r < 4; ++r) {
        int m = m0 + wy * 64 + mt * 16 + 4 * g + r;
        int bl = m >> 13, s = m & 8191;
        size_t bh = (size_t)bl * NHEADS + h;
        dst[(bh * SEQ + s) * HDIM + d] = f2bf(a[r] + bval);
      }
    }
  }
}

// ---------------------------------------------------------------------------
// MFMA attention — T14 async staging; full-posk prestage; minimal barriers.
__global__ __launch_bounds__(512, 2) void attn_kernel(
    const unsigned short* __restrict__ qws, const unsigned short* __restrict__ kws,
    const unsigned short* __restrict__ vws, const unsigned short* __restrict__ posq,
    const unsigned short* __restrict__ posk, unsigned short* __restrict__ ctx) {
  extern __shared__ char smem[];
  int* iLUT = (int*)(smem + LUT_OFF);
  unsigned short* C2P = (unsigned short*)(smem + C2P_OFF);

  const int tid = threadIdx.x;
  const int wave = tid >> 6;
  const int lane = tid & 63;
  const int l15 = lane & 15;
  const int g = lane >> 4;
  const int qs = wave << 4;

  const int n = blockIdx.x & 63;
  const int bh = blockIdx.x >> 6;
  const int h = bh % NHEADS;
  const int b = bh / NHEADS;

  const unsigned short* kbh = kws + (size_t)bh * SEQ * HDIM;
  const unsigned short* vbh = vws + (size_t)bh * SEQ * HDIM;
  const unsigned short* pqh = posq + (size_t)h * PBUCK * HDIM;
  const unsigned short* pkh = posk + (size_t)h * PBUCK * HDIM;

  // ---- phase 0: Q fragments DIRECT from global; stage FULL posk; LUT
  bf16x8 qf0, qf1;
  {
    const unsigned short* qp =
        qws + ((size_t)bh * SEQ + n * BSZ + qs + l15) * HDIM;
    union { bf16x8 v; uint2 u2[2]; } u0, u1;
    u0.u2[0] = *(const uint2*)(qp + g * 4);
    u0.u2[1] = *(const uint2*)(qp + 16 + g * 4);
    u1.u2[0] = *(const uint2*)(qp + 32 + g * 4);
    u1.u2[1] = *(const uint2*)(qp + 48 + g * 4);
    qf0 = u0.v; qf1 = u1.v;
  }
  for (int idx = tid; idx < 192 * 8; idx += 512) {
    int row = idx >> 3, c = idx & 7;
    uint4 v = *(const uint4*)(pkh + row * HDIM + c * 8);
    stfrag(smem + PKH_OFF, row, 128, c, v);
  }
  for (int idx = tid; idx < 192 * 8; idx += 512) {
    int row = idx >> 3, c = idx & 7;
    uint4 v = *(const uint4*)(pkh + (192 + row) * HDIM + c * 8);
    stfrag(smem + PK2_OFF, row, 128, c, v);
  }
  if (tid < 511) iLUT[tid] = bucket_idx(tid - 383);
  __syncthreads();  // B1

  // ---- phase 1: C2P_all[q][p] = Q . posk^T, single 24-tile loop
  __builtin_amdgcn_s_setprio(1);
#pragma unroll
  for (int ntl = 0; ntl < 24; ++ntl) {
    const int base = (ntl < 12) ? PKH_OFF : PK2_OFF;
    const int prow = ((ntl < 12) ? 16 * ntl : 16 * (ntl - 12)) + l15;
    bf16x8 b0 = ldfrag128(smem, base, prow, 128, 0, g);
    bf16x8 b1 = ldfrag128(smem, base, prow, 128, 1, g);
    f32x4 c = {0.f, 0.f, 0.f, 0.f};
    c = MFMA16(qf0, b0, c);
    c = MFMA16(qf1, b1, c);
    int p = 16 * ntl + l15;
#pragma unroll
    for (int r = 0; r < 4; ++r)
      C2P[(qs + 4 * g + r) * C2PS + p] = f2bf(c[r]);
  }
  __builtin_amdgcn_s_setprio(0);

  // T14: issue K/PQ prefetch NOW — in flight under the phase-2 gather.
  uint4 kpre[6], ppre[6];
#pragma unroll
  for (int i = 0; i < 6; ++i) {
    int idx = tid + i * 512;
    int row = idx >> 3, c = idx & 7;
    int ks = n * BSZ - BSZ + row;
    kpre[i] = make_uint4(0u, 0u, 0u, 0u);
    if (ks >= 0 && ks < SEQ)
      kpre[i] = *(const uint4*)(kbh + (size_t)ks * HDIM + c * 8);
    ppre[i] = *(const uint4*)(pqh + (size_t)row * HDIM + c * 8);
  }

  // No barrier: each wave gathers ONLY from its own 16-row C2P strip.
  asm volatile("s_waitcnt lgkmcnt(0)" ::: "memory");
  __builtin_amdgcn_sched_barrier(0);

  // ---- phase 2: gather c2p into acc
  f32x4 acc[24];
  {
    const int qrow = qs + l15;
    const unsigned short* c2pRow = C2P + qrow * C2PS;
    const int dbase = qrow - 4 * g + 383;
#pragma unroll
    for (int t = 0; t < 24; ++t) {
#pragma unroll
      for (int r = 0; r < 4; ++r) {
        int idx = iLUT[dbase - 16 * t - r];
        acc[t][r] = bf2f(c2pRow[idx]);
      }
    }
  }
  __syncthreads();  // B2: C2P dead

  // ---- phase 3: write prefetched K and posq into LDS (loads already done)
#pragma unroll
  for (int i = 0; i < 6; ++i) {
    int idx = tid + i * 512;
    int row = idx >> 3, c = idx & 7;
    stfrag(smem + K_OFF, row, 128, c, kpre[i]);
    stfrag(smem + PQ_OFF, row, 128, c, ppre[i]);
  }
  __syncthreads();  // B3

  // ---- phase 4: p2c, 12 subtiles; Tl double-buffered (slot s&1)
#pragma unroll
  for (int s = 0; s < 12; ++s) {
    unsigned short* Tl =
        (unsigned short*)(smem + ((s & 1) ? Q_OFF : T_OFF));
    const int lo = iLUT[352 - 32 * s];
    const int hi = iLUT[510 - 32 * s];
    const int ntiles = ((hi - lo + 1) + 15) >> 4;
    for (int tl = wave; tl < 2 * ntiles; tl += 8) {
      int mt = tl & 1, ntl = tl >> 1;
      bf16x8 a0 = ldfrag128(smem, K_OFF, 32 * s + 16 * mt + l15, 128, 0, g);
      bf16x8 a1 = ldfrag128(smem, K_OFF, 32 * s + 16 * mt + l15, 128, 1, g);
      int prow = lo + 16 * ntl + l15;
      prow = prow > 383 ? 383 : prow;
      bf16x8 b0 = ldfrag128(smem, PQ_OFF, prow, 128, 0, g);
      bf16x8 b1 = ldfrag128(smem, PQ_OFF, prow, 128, 1, g);
      f32x4 c = {0.f, 0.f, 0.f, 0.f};
      c = MFMA16(a0, b0, c);
      c = MFMA16(a1, b1, c);
#pragma unroll
      for (int r = 0; r < 4; ++r)
        Tl[(16 * mt + 4 * g + r) * TLS + 16 * ntl + l15] = f2bf(c[r]);
    }
    __syncthreads();  // Tl[s&1] ready; next iteration writes the OTHER slot
    {
      const int dbase2 = qs + l15 - 32 * s - 4 * g + 383;
#pragma unroll
      for (int tt = 0; tt < 2; ++tt) {
#pragma unroll
        for (int r = 0; r < 4; ++r) {
          int idx = iLUT[dbase2 - 16 * tt - r];
          acc[2 * s + tt][r] += bf2f(Tl[(16 * tt + 4 * g + r) * TLS + idx - lo]);
        }
      }
    }
  }

  // T14: issue Vt prefetch NOW — covered by phase-5 MFMAs.
  uint4 vpa[3], vpb[3];
#pragma unroll
  for (int i = 0; i < 3; ++i) {
    int idx = tid + i * 512;
    int u2i = idx % 192;
    int dg = idx / 192;
    int s0v = 2 * u2i;
    int ks0 = n * BSZ - BSZ + s0v;
    vpa[i] = make_uint4(0u, 0u, 0u, 0u);
    vpb[i] = make_uint4(0u, 0u, 0u, 0u);
    if (ks0 >= 0 && ks0 < SEQ)
      vpa[i] = *(const uint4*)(vbh + (size_t)ks0 * HDIM + dg * 8);
    if (ks0 + 1 >= 0 && ks0 + 1 < SEQ)
      vpb[i] = *(const uint4*)(vbh + (size_t)(ks0 + 1) * HDIM + dg * 8);
  }

  // ---- phase 5: QK^T accumulate. No barrier needed: reads K [0,48K) only;
  // other waves' trailing s=11 gathers read Tl [101K+); Vt writes below hit
  // [48K,96K) — all pairwise disjoint, fenced by phase-4's last barrier.
  __builtin_amdgcn_s_setprio(1);
#pragma unroll
  for (int t = 0; t < 24; ++t) {
    bf16x8 a0 = ldfrag128(smem, K_OFF, 16 * t + l15, 128, 0, g);
    bf16x8 a1 = ldfrag128(smem, K_OFF, 16 * t + l15, 128, 1, g);
    acc[t] = MFMA16(a0, qf0, acc[t]);
    acc[t] = MFMA16(a1, qf1, acc[t]);
  }
  __builtin_amdgcn_s_setprio(0);

  // ---- phase 6: write prefetched Vt (packed b32, transposed layout)
#pragma unroll
  for (int i = 0; i < 3; ++i) {
    int idx = tid + i * 512;
    int u2i = idx % 192;
    int dg = idx / 192;
    const int nc = 2 * vperm(2 * u2i);
    union { uint4 q; unsigned short u[8]; } wa, wb;
    wa.q = vpa[i]; wb.q = vpb[i];
#pragma unroll
    for (int j = 0; j < 8; ++j) {
      int d = dg * 8 + j;
      unsigned int pk = (unsigned int)wa.u[j] | ((unsigned int)wb.u[j] << 16);
      *(unsigned int*)(smem + VT_OFF + d * 768 + (nc ^ ((d & 7) << 4))) = pk;
    }
  }

  // ---- phase 7: softmax (in-register; q = qs + l15 fixed per lane)
  float m = -1e30f;
#pragma unroll
  for (int t = 0; t < 24; ++t)
#pragma unroll
    for (int r = 0; r < 4; ++r) m = fmaxf(m, acc[t][r]);
  m = fmaxf(m, __shfl_xor(m, 16));
  m = fmaxf(m, __shfl_xor(m, 32));
  float sum = 0.f;
#pragma unroll
  for (int t = 0; t < 24; ++t)
#pragma unroll
    for (int r = 0; r < 4; ++r) {
      float p = exp2f((acc[t][r] - m) * 0.10411790f);  // /sqrt(192) * log2e
      acc[t][r] = p;
      sum += p;
    }
  sum += __shfl_xor(sum, 16);
  sum += __shfl_xor(sum, 32);
  float inv = 1.0f / sum;

  bf16x8 pa[12];
#pragma unroll
  for (int kt = 0; kt < 12; ++kt) {
    union { bf16x8 v; unsigned short u[8]; } w;
#pragma unroll
    for (int j = 0; j < 4; ++j) w.u[j] = f2bf(acc[2 * kt][j] * inv);
#pragma unroll
    for (int j = 0; j < 4; ++j) w.u[4 + j] = f2bf(acc[2 * kt + 1][j] * inv);
    pa[kt] = w.v;
  }
  __syncthreads();  // Vt staged (all waves' writes visible)

  // ---- phase 8: PV, write ctx bf16
  unsigned short* ctxg = ctx + ((size_t)b * SEQ + n * BSZ) * HID + h * HDIM;
  __builtin_amdgcn_s_setprio(1);
#pragma unroll
  for (int nt = 0; nt < 4; ++nt) {
    f32x4 o = {0.f, 0.f, 0.f, 0.f};
#pragma unroll
    for (int kt = 0; kt < 12; ++kt) {
      bf16x8 bv = ldfrag128(smem, VT_OFF, 16 * nt + l15, 768, kt, g);
      o = MFMA16(pa[kt], bv, o);
    }
#pragma unroll
    for (int r = 0; r < 4; ++r) {
      size_t off = (size_t)(qs + 4 * g + r) * HID + 16 * nt + l15;
      ctxg[off] = f2bf(o[r]);
    }
  }
  __builtin_amdgcn_s_setprio(0);
}

// ---------------------------------------------------------------------------
// Fused out-projection + bias + residual + LayerNorm.
__global__ __launch_bounds__(512) void out_ln(
    const unsigned short* __restrict__ ctx, const unsigned short* __restrict__ WoT,
    const float* __restrict__ bo, const float* __restrict__ hidden,
    const float* __restrict__ lns, const float* __restrict__ lnb,
    float* __restrict__ out) {
  extern __shared__ char smem[];
  unsigned short* Au = (unsigned short*)(smem + OL_AU);
  unsigned short* Bu = (unsigned short*)(smem + OL_BU);
  float* red1 = (float*)(smem + OL_R1);
  float* red2 = (float*)(smem + OL_R2);
  float* muA = (float*)(smem + OL_MU);
  float* rsA = (float*)(smem + OL_RS);

  const int t = threadIdx.x;
  const int lane = t & 63;
  const int l15 = lane & 15, g = lane >> 4;
  const int w = t >> 6;
  const int m0 = blockIdx.x * 64;

  f32x4 acc[4][6];
#pragma unroll
  for (int mt = 0; mt < 4; ++mt)
#pragma unroll
    for (int nt = 0; nt < 6; ++nt) acc[mt][nt] = (f32x4){0.f, 0.f, 0.f, 0.f};

  for (int k0 = 0; k0 < HID; k0 += 32) {
    if (t < 256) {
      int r = t >> 2, c = t & 3;
      uint4 v = *(const uint4*)(ctx + (size_t)(m0 + r) * HID + k0 + c * 8);
      *(uint4*)(Au + r * 40 + c * 8) = v;
    }
#pragma unroll
    for (int i = 0; i < 6; ++i) {
      int idx = t + i * 512;
      int nrow = idx >> 2, c = idx & 3;
      uint4 v = *(const uint4*)(WoT + (size_t)nrow * HID + k0 + c * 8);
      *(uint4*)(Bu + nrow * 40 + c * 8) = v;
    }
    __syncthreads();
    bf16x8 af[4];
#pragma unroll
    for (int mt = 0; mt < 4; ++mt) af[mt] = olfrag(Au, mt * 16 + l15, g);
#pragma unroll
    for (int nt = 0; nt < 6; ++nt) {
      bf16x8 bf = olfrag(Bu, w * 96 + nt * 16 + l15, g);
#pragma unroll
      for (int mt = 0; mt < 4; ++mt)
        acc[mt][nt] = MFMA16(af[mt], bf, acc[mt][nt]);
    }
    __syncthreads();
  }

  float psum[4][4] = {};
  float psq[4][4] = {};
#pragma unroll
  for (int nt = 0; nt < 6; ++nt) {
    int gn = w * 96 + nt * 16 + l15;
    float bval = bo[gn];
#pragma unroll
    for (int mt = 0; mt < 4; ++mt) {
#pragma unroll
      for (int r = 0; r < 4; ++r) {
        int gm = m0 + mt * 16 + 4 * g + r;
        float v = acc[mt][nt][r] + bval + hidden[(size_t)gm * HID + gn];
        acc[mt][nt][r] = v;
        psum[mt][r] += v;
        psq[mt][r] += v * v;
      }
    }
  }
#pragma unroll
  for (int o = 1; o < 16; o <<= 1) {
#pragma unroll
    for (int mt = 0; mt < 4; ++mt)
#pragma unroll
      for (int r = 0; r < 4; ++r) {
        psum[mt][r] += __shfl_xor(psum[mt][r], o);
        psq[mt][r] += __shfl_xor(psq[mt][r], o);
      }
  }
  if (l15 == 0) {
#pragma unroll
    for (int mt = 0; mt < 4; ++mt)
#pragma unroll
      for (int r = 0; r < 4; ++r) {
        red1[(mt * 16 + 4 * g + r) * 8 + w] = psum[mt][r];
        red2[(mt * 16 + 4 * g + r) * 8 + w] = psq[mt][r];
      }
  }
  __syncthreads();
  if (t < 64) {
    float s = 0.f, s2 = 0.f;
#pragma unroll
    for (int i = 0; i < 8; ++i) {
      s += red1[t * 8 + i];
      s2 += red2[t * 8 + i];
    }
    float mu = s * (1.0f / 768.0f);
    float var = s2 * (1.0f / 768.0f) - mu * mu;
    muA[t] = mu;
    rsA[t] = 1.0f / sqrtf(var + 1e-7f);
  }
  __syncthreads();
#pragma unroll
  for (int nt = 0; nt < 6; ++nt) {
    int gn = w * 96 + nt * 16 + l15;
    float sc = lns[gn], bi = lnb[gn];
#pragma unroll
    for (int mt = 0; mt < 4; ++mt) {
#pragma unroll
      for (int r = 0; r < 4; ++r) {
        int lm = mt * 16 + 4 * g + r;
        float v = (acc[mt][nt][r] - muA[lm]) * rsA[lm] * sc + bi;
        out[(size_t)(m0 + lm) * HID + gn] = v;
      }
    }
  }
}

extern "C" void kernel_launch(void* const* d_in, const int* in_sizes, int n_in,
                              void* d_out, int out_size, void* d_ws,
                              size_t ws_size, hipStream_t stream) {
  (void)in_sizes; (void)n_in; (void)out_size; (void)ws_size;
  const float* hidden = (const float*)d_in[0];
  const float* relpos = (const float*)d_in[1];
  const float* Wq = (const float*)d_in[2];
  const float* bq = (const float*)d_in[3];
  const float* Wk = (const float*)d_in[4];
  const float* bk = (const float*)d_in[5];
  const float* Wv = (const float*)d_in[6];
  const float* bv = (const float*)d_in[7];
  const float* Wo = (const float*)d_in[8];
  const float* bo = (const float*)d_in[9];
  const float* lns = (const float*)d_in[10];
  const float* lnb = (const float*)d_in[11];
  float* out = (float*)d_out;

  // Workspace (ushort units), total 207,618,048 B == proven footprint.
  unsigned short* ws = (unsigned short*)d_ws;
  const size_t QE = (size_t)48 * SEQ * HDIM;   // 25,165,824
  const size_t PE = (size_t)NHEADS * PBUCK * HDIM;  // 393,216
  unsigned short* qws = ws;
  unsigned short* kws = qws + QE;
  unsigned short* vws = kws + QE;
  unsigned short* ctx = vws + QE;
  unsigned short* hbf = ctx;                   // alias: dead before attn writes
  unsigned short* posq = ctx + QE;
  unsigned short* posk = posq + PE;
  unsigned short* Wt4 = posk + PE;             // 4 x 589,824
  unsigned short* WoT = Wt4 + (size_t)3 * HID * HID;

  static bool attrib_set = false;
  if (!attrib_set) {
    hipFuncSetAttribute((const void*)attn_kernel,
                        hipFuncAttributeMaxDynamicSharedMemorySize, SMEM_ATTN);
    hipFuncSetAttribute((const void*)out_ln,
                        hipFuncAttributeMaxDynamicSharedMemorySize, SMEM_OL);
    attrib_set = true;
  }

  hbf_conv<<<12288, 256, 0, stream>>>(hidden, hbf);
  conv_wt<<<dim3(12, 12, 4), 256, 0, stream>>>(Wq, Wk, Wv, Wo, Wt4);
  pos_gemm<<<dim3(8, 24), 256, 0, stream>>>(relpos, Wq, Wk, bq, bk, posq, posk);
  qkv_mfma<<<4608, 256, 0, stream>>>(hbf, Wt4, bq, bk, bv, qws, kws, vws);
  attn_kernel<<<3072, 512, SMEM_ATTN, stream>>>(qws, kws, vws, posq, posk, ctx);
  out_ln<<<512, 512, SMEM_OL, stream>>>(ctx, WoT, bo, hidden, lns, lnb, out);
}

// Round 17
// 674.751 us; speedup vs baseline: 1.0429x; 1.0429x over previous
//
#include <hip/hip_runtime.h>
#include <math.h>

// ---------------------------------------------------------------------------
// LocalSlidingWindow_DisentangledAttention — Round 17: exact R15 restore
// (best: 679us). R16's register prefetch REVERTED (spilled to scratch:
// WRITE_SIZE 49K->153K KB, attn +22us).
// Kernel set: hbf_conv, conv_wt, pos_gemm, qkv_mfma (glds staging, XCD
// swizzle), attn (fragment-major b128 frags, C2PS 396, Tl double-buffer,
// setprio, packed-VT), fused out_ln. Workspace = 207,618,048 B (proven).
// ---------------------------------------------------------------------------

#define NHEADS 12
#define HDIM   64
#define SEQ    8192
#define HID    768
#define BSZ    128
#define WIN    384
#define PBUCK  512

typedef __attribute__((ext_vector_type(8))) short bf16x8;
typedef __attribute__((ext_vector_type(4))) float f32x4;
#define MFMA16(a, b, c) __builtin_amdgcn_mfma_f32_16x16x32_bf16((a), (b), (c), 0, 0, 0)

// attn LDS byte map (dynamic, 156288 total)
#define C2PS    396      // C2P row stride (ushorts)
#define TLS     186      // Tl row stride (ushorts)
#define C2P_OFF 0        // [128][396] bf16 = 101376   (phase 1-2)
#define K_OFF   0        // [384][64]  bf16 = 49152    (phase 3+)
#define PQ_OFF  49152    // [384][64]  bf16 = 49152    (phase 3-4)
#define VT_OFF  49152    // [64][384]  bf16 = 49152    (PV phase)
#define T_OFF   101376   // Tl slot0 [32][186] bf16 = 11904
#define Q_OFF   113280   // [128][64]  bf16 = 16384 (phase 0-1; Tl slot1 after)
#define PKH_OFF 129664   // [192][64]  bf16 = 24576
#define LUT_OFF 154240   // [511] int  = 2044
#define SMEM_ATTN 156288

// out_ln LDS byte map (dynamic, 71168)
#define OL_AU 0          // [64][40] bf16 = 5120
#define OL_BU 5120       // [768][40] bf16 = 61440
#define OL_R1 66560      // [64][8] f32 = 2048
#define OL_R2 68608      // [64][8] f32 = 2048
#define OL_MU 70656      // [64] f32
#define OL_RS 70912      // [64] f32
#define SMEM_OL 71168

typedef __attribute__((address_space(3))) unsigned int lds_uint;
typedef const __attribute__((address_space(1))) unsigned int glob_uint;

__device__ __forceinline__ unsigned short f2bf(float f) {
  unsigned int x = __builtin_bit_cast(unsigned int, f);
  unsigned int r = (x + 0x7FFFu + ((x >> 16) & 1u)) >> 16;
  return (unsigned short)r;
}
__device__ __forceinline__ float bf2f(unsigned short u) {
  unsigned int x = ((unsigned int)u) << 16;
  return __builtin_bit_cast(float, x);
}

// idx(rel) for rel in [-383, 127]
__device__ __forceinline__ int bucket_idx(int rel) {
  if (rel >= -128) return rel + 256;
  float a = (float)(-rel);
  float t = logf(a * (1.0f / 128.0f));
  t = t / 0.6892332813f;
  t = t * 127.0f;
  int lp = (int)(ceilf(t) + 128.0f);
  int r = 256 - lp;
  return r < 0 ? 0 : r;
}

// ---- fragment-major layout helpers (attn) ----
__device__ __forceinline__ bf16x8 ldfrag128(const char* sm, int byteBase,
                                            int row, int rowBytes, int slice,
                                            int g) {
  const int swz = (row & 7) << 4;
  return *(const bf16x8*)(sm + byteBase + row * rowBytes +
                          (((slice << 6) + (g << 4)) ^ swz));
}
__device__ __forceinline__ void stfrag(char* base, int row, int rowBytes,
                                       int c, uint4 v) {
  const int swz = (row & 7) << 4;
  const int s = c >> 2, h = (c >> 1) & 1;
  const int n1 = s * 64 + ((2 * c) & 3) * 16 + h * 8;
  const int n2 = s * 64 + ((2 * c + 1) & 3) * 16 + h * 8;
  char* p = base + row * rowBytes;
  *(uint2*)(p + (n1 ^ swz)) = make_uint2(v.x, v.y);
  *(uint2*)(p + (n2 ^ swz)) = make_uint2(v.z, v.w);
}
__device__ __forceinline__ int vperm(int o) {
  return (o & ~31) + (((o >> 2) & 3) << 3) + (((o >> 4) & 1) << 2) + (o & 3);
}

// old-layout fragment read (qkv/out_ln: 2x8B pattern)
__device__ __forceinline__ bf16x8 ldfrag(const char* sm, int byteBase, int row,
                                         int rowBytes, int slice, int g) {
  const int swz = (row & 7) << 4;
  const char* p = sm + byteBase + row * rowBytes;
  union { bf16x8 v; uint2 u2[2]; } w;
  w.u2[0] = *(const uint2*)(p + (((slice << 6) + (g << 3)) ^ swz));
  w.u2[1] = *(const uint2*)(p + (((slice << 6) + 32 + (g << 3)) ^ swz));
  return w.v;
}

// Fragment from padded (40-ushort rows, no swizzle) LDS tile for out_ln.
__device__ __forceinline__ bf16x8 olfrag(const unsigned short* base, int row,
                                         int g) {
  const unsigned short* p = base + row * 40 + 4 * g;
  union { bf16x8 v; uint2 u2[2]; } w;
  w.u2[0] = *(const uint2*)(p);
  w.u2[1] = *(const uint2*)(p + 16);
  return w.v;
}

// ---------------------------------------------------------------------------
// hidden fp32 -> bf16
__global__ __launch_bounds__(256) void hbf_conv(const float* __restrict__ src,
                                                unsigned short* __restrict__ dst) {
  size_t i = ((size_t)blockIdx.x * 256 + threadIdx.x) * 8;
  float4 a = *(const float4*)(src + i);
  float4 b = *(const float4*)(src + i + 4);
  union { uint4 q; unsigned short u[8]; } w;
  w.u[0] = f2bf(a.x); w.u[1] = f2bf(a.y); w.u[2] = f2bf(a.z); w.u[3] = f2bf(a.w);
  w.u[4] = f2bf(b.x); w.u[5] = f2bf(b.y); w.u[6] = f2bf(b.z); w.u[7] = f2bf(b.w);
  *(uint4*)(dst + i) = w.q;
}

// Weight transpose fp32 -> bf16: Wt[z*768 + n][k] = W_z[k][n], z = 0..3
__global__ __launch_bounds__(256) void conv_wt(const float* __restrict__ W0,
                                               const float* __restrict__ W1,
                                               const float* __restrict__ W2,
                                               const float* __restrict__ W3,
                                               unsigned short* __restrict__ Wt) {
  __shared__ float tile[64][65];
  int bx = blockIdx.x, by = blockIdx.y, z = blockIdx.z;
  const float* W = (z == 0) ? W0 : (z == 1 ? W1 : (z == 2 ? W2 : W3));
  int t = threadIdx.x;
  int c = t & 63, r0 = (t >> 6) * 16;
#pragma unroll
  for (int rr = 0; rr < 16; ++rr)
    tile[r0 + rr][c] = W[(size_t)(by * 64 + r0 + rr) * HID + bx * 64 + c];
  __syncthreads();
#pragma unroll
  for (int rr = 0; rr < 16; ++rr) {
    int nw = r0 + rr;
    Wt[((size_t)z * HID + bx * 64 + nw) * HID + by * 64 + c] = f2bf(tile[c][nw]);
  }
}

// Positional projection (fp32 math) -> bf16 posq/posk [h][512][64]
__global__ __launch_bounds__(256) void pos_gemm(
    const float* __restrict__ relpos, const float* __restrict__ Wq,
    const float* __restrict__ Wk, const float* __restrict__ bq,
    const float* __restrict__ bk, unsigned short* __restrict__ posq,
    unsigned short* __restrict__ posk) {
  __shared__ float At[32][68];
  __shared__ float Bs[32][68];
  int m0 = blockIdx.x * 64;
  int n0 = blockIdx.y * 64;
  int w = n0 / HID;
  int nc0 = n0 % HID;
  const float* W = (w == 0) ? Wq : Wk;
  const float* bias = (w == 0) ? bq : bk;
  int t = threadIdx.x;
  int tx = t & 15, ty = t >> 4;
  float acc[4][4] = {};
  for (int k0 = 0; k0 < HID; k0 += 32) {
#pragma unroll
    for (int u = 0; u < 2; ++u) {
      int f = t * 2 + u;
      int r = f >> 3, c4 = f & 7;
      float4 av = *(const float4*)(relpos + (size_t)(m0 + r) * HID + k0 + c4 * 4);
      At[c4 * 4 + 0][r] = av.x; At[c4 * 4 + 1][r] = av.y;
      At[c4 * 4 + 2][r] = av.z; At[c4 * 4 + 3][r] = av.w;
    }
#pragma unroll
    for (int u = 0; u < 2; ++u) {
      int f = t * 2 + u;
      int kk = f >> 4, c4 = f & 15;
      float4 bv4 = *(const float4*)(W + (size_t)(k0 + kk) * HID + nc0 + c4 * 4);
      *(float4*)&Bs[kk][c4 * 4] = bv4;
    }
    __syncthreads();
#pragma unroll
    for (int kk = 0; kk < 32; ++kk) {
      float4 a4 = *(const float4*)&At[kk][ty * 4];
      float4 b4 = *(const float4*)&Bs[kk][tx * 4];
      float av[4] = {a4.x, a4.y, a4.z, a4.w};
      float bvv[4] = {b4.x, b4.y, b4.z, b4.w};
#pragma unroll
      for (int i = 0; i < 4; ++i)
#pragma unroll
        for (int jj = 0; jj < 4; ++jj) acc[i][jj] += av[i] * bvv[jj];
    }
    __syncthreads();
  }
  int h = nc0 >> 6;
  unsigned short* dst = (w == 0) ? posq : posk;
#pragma unroll
  for (int i = 0; i < 4; ++i) {
    int p = m0 + ty * 4 + i;
    ushort4 o;
    o.x = f2bf(acc[i][0] + bias[nc0 + tx * 4 + 0]);
    o.y = f2bf(acc[i][1] + bias[nc0 + tx * 4 + 1]);
    o.z = f2bf(acc[i][2] + bias[nc0 + tx * 4 + 2]);
    o.w = f2bf(acc[i][3] + bias[nc0 + tx * 4 + 3]);
    *(ushort4*)(dst + ((size_t)h * PBUCK + p) * HDIM + tx * 4) = o;
  }
}

// ---------------------------------------------------------------------------
// QKV projection, bf16 MFMA. Tile 128x128, BK=64, 256 thr = 4 waves (2x2).
// Staging via global_load_lds width-16 (pre-swizzled global source).
__global__ __launch_bounds__(256) void qkv_mfma(
    const unsigned short* __restrict__ hbf, const unsigned short* __restrict__ Wt,
    const float* __restrict__ bq, const float* __restrict__ bk,
    const float* __restrict__ bv, unsigned short* __restrict__ qws,
    unsigned short* __restrict__ kws, unsigned short* __restrict__ vws) {
  __shared__ unsigned short As[8192];
  __shared__ unsigned short Bs[8192];
  const int t = threadIdx.x;
  const int lane = t & 63;
  const int l15 = lane & 15, g = lane >> 4;
  const int wave = t >> 6;
  const int wy = wave >> 1, wx = wave & 1;
  const int bid = blockIdx.x;
  const int wg = (bid & 7) * 576 + (bid >> 3);
  const int n0 = (wg % 18) * 128;
  const int m0 = (wg / 18) * 128;

  const int rsub = lane >> 3;
  const int slot = lane & 7;

  f32x4 acc[4][4];
#pragma unroll
  for (int i = 0; i < 4; ++i)
#pragma unroll
    for (int j = 0; j < 4; ++j) acc[i][j] = (f32x4){0.f, 0.f, 0.f, 0.f};

  for (int k0 = 0; k0 < HID; k0 += 64) {
#pragma unroll
    for (int i = 0; i < 4; ++i) {
      int row = wave * 32 + i * 8 + rsub;
      int cx = slot ^ (row & 7);
      const unsigned short* src = hbf + (size_t)(m0 + row) * HID + k0 + cx * 8;
      __builtin_amdgcn_global_load_lds(
          (glob_uint*)src, (lds_uint*)((char*)As + wave * 4096 + i * 1024),
          16, 0, 0);
    }
#pragma unroll
    for (int i = 0; i < 4; ++i) {
      int row = wave * 32 + i * 8 + rsub;
      int cx = slot ^ (row & 7);
      const unsigned short* src = Wt + (size_t)(n0 + row) * HID + k0 + cx * 8;
      __builtin_amdgcn_global_load_lds(
          (glob_uint*)src, (lds_uint*)((char*)Bs + wave * 4096 + i * 1024),
          16, 0, 0);
    }
    __syncthreads();
    bf16x8 af[4][2], bf[4][2];
#pragma unroll
    for (int mt = 0; mt < 4; ++mt) {
      int row = wy * 64 + mt * 16 + l15;
#pragma unroll
      for (int s = 0; s < 2; ++s)
        af[mt][s] = ldfrag((const char*)As, 0, row, 128, s, g);
    }
#pragma unroll
    for (int nt = 0; nt < 4; ++nt) {
      int row = wx * 64 + nt * 16 + l15;
#pragma unroll
      for (int s = 0; s < 2; ++s)
        bf[nt][s] = ldfrag((const char*)Bs, 0, row, 128, s, g);
    }
#pragma unroll
    for (int mt = 0; mt < 4; ++mt)
#pragma unroll
      for (int nt = 0; nt < 4; ++nt) {
        acc[mt][nt] = MFMA16(af[mt][0], bf[nt][0], acc[mt][nt]);
        acc[mt][nt] = MFMA16(af[mt][1], bf[nt][1], acc[mt][nt]);
      }
    __syncthreads();
  }

  const int w = n0 / HID;  // 0:q 1:k 2:v
  const float* bias = (w == 0) ? bq : (w == 1 ? bk : bv);
  unsigned short* dst = (w == 0) ? qws : (w == 1 ? kws : vws);
#pragma unroll
  for (int nt = 0; nt < 4; ++nt) {
    int gn = n0 + wx * 64 + nt * 16 + l15;
    int nc = gn - w * HID;
    int h = nc >> 6, d = nc & 63;
    float bval = bias[nc];
#pragma unroll
    for (int mt = 0; mt < 4; ++mt) {
      f32x4 a = acc[mt][nt];
#pragma unroll
      for (int r = 0; r < 4; ++r) {
        int m = m0 + wy * 64 + mt * 16 + 4 * g + r;
        int bl = m >> 13, s = m & 8191;
        size_t bh = (size_t)bl * NHEADS + h;
        dst[(bh * SEQ + s) * HDIM + d] = f2bf(a[r] + bval);
      }
    }
  }
}

// ---------------------------------------------------------------------------
// MFMA attention — fragment-major LDS tiles; setprio; double-buffered Tl.
__global__ __launch_bounds__(512, 2) void attn_kernel(
    const unsigned short* __restrict__ qws, const unsigned short* __restrict__ kws,
    const unsigned short* __restrict__ vws, const unsigned short* __restrict__ posq,
    const unsigned short* __restrict__ posk, unsigned short* __restrict__ ctx) {
  extern __shared__ char smem[];
  int* iLUT = (int*)(smem + LUT_OFF);
  unsigned short* C2P = (unsigned short*)(smem + C2P_OFF);

  const int tid = threadIdx.x;
  const int wave = tid >> 6;
  const int lane = tid & 63;
  const int l15 = lane & 15;
  const int g = lane >> 4;
  const int qs = wave << 4;

  const int n = blockIdx.x & 63;
  const int bh = blockIdx.x >> 6;
  const int h = bh % NHEADS;
  const int b = bh / NHEADS;

  const unsigned short* qsrc = qws + ((size_t)bh * SEQ + n * BSZ) * HDIM;
  const unsigned short* kbh = kws + (size_t)bh * SEQ * HDIM;
  const unsigned short* vbh = vws + (size_t)bh * SEQ * HDIM;
  const unsigned short* pqh = posq + (size_t)h * PBUCK * HDIM;
  const unsigned short* pkh = posk + (size_t)h * PBUCK * HDIM;

  // ---- phase 0: stage Q, posk half 0, fill LUT (fragment-major)
  for (int idx = tid; idx < 128 * 8; idx += 512) {
    int row = idx >> 3, c = idx & 7;
    uint4 v = *(const uint4*)(qsrc + row * HDIM + c * 8);
    stfrag(smem + Q_OFF, row, 128, c, v);
  }
  for (int idx = tid; idx < 192 * 8; idx += 512) {
    int row = idx >> 3, c = idx & 7;
    uint4 v = *(const uint4*)(pkh + row * HDIM + c * 8);
    stfrag(smem + PKH_OFF, row, 128, c, v);
  }
  if (tid < 511) iLUT[tid] = bucket_idx(tid - 383);
  __syncthreads();

  bf16x8 qf0 = ldfrag128(smem, Q_OFF, qs + l15, 128, 0, g);
  bf16x8 qf1 = ldfrag128(smem, Q_OFF, qs + l15, 128, 1, g);

  // ---- phase 1: C2P_all[q][p] = Q . posk^T  (two halves of 192 p)
#pragma unroll
  for (int half = 0; half < 2; ++half) {
    if (half) {
      __syncthreads();
      for (int idx = tid; idx < 192 * 8; idx += 512) {
        int row = idx >> 3, c = idx & 7;
        uint4 v = *(const uint4*)(pkh + (192 + row) * HDIM + c * 8);
        stfrag(smem + PKH_OFF, row, 128, c, v);
      }
      __syncthreads();
    }
    __builtin_amdgcn_s_setprio(1);
    for (int ntl = 0; ntl < 12; ++ntl) {
      bf16x8 b0 = ldfrag128(smem, PKH_OFF, 16 * ntl + l15, 128, 0, g);
      bf16x8 b1 = ldfrag128(smem, PKH_OFF, 16 * ntl + l15, 128, 1, g);
      f32x4 c = {0.f, 0.f, 0.f, 0.f};
      c = MFMA16(qf0, b0, c);
      c = MFMA16(qf1, b1, c);
      int p = half * 192 + 16 * ntl + l15;
#pragma unroll
      for (int r = 0; r < 4; ++r)
        C2P[(qs + 4 * g + r) * C2PS + p] = f2bf(c[r]);
    }
    __builtin_amdgcn_s_setprio(0);
  }
  // No barrier: each wave gathers ONLY from its own 16-row C2P strip.
  asm volatile("s_waitcnt lgkmcnt(0)" ::: "memory");
  __builtin_amdgcn_sched_barrier(0);

  // ---- phase 2: gather c2p into acc
  f32x4 acc[24];
  {
    const int qrow = qs + l15;
    const unsigned short* c2pRow = C2P + qrow * C2PS;
    const int dbase = qrow - 4 * g + 383;
#pragma unroll
    for (int t = 0; t < 24; ++t) {
#pragma unroll
      for (int r = 0; r < 4; ++r) {
        int idx = iLUT[dbase - 16 * t - r];
        acc[t][r] = bf2f(c2pRow[idx]);
      }
    }
  }
  __syncthreads();  // C2P dead

  // ---- phase 3: stage K and posq (zero-fill outside [0,SEQ))
  for (int idx = tid; idx < 384 * 8; idx += 512) {
    int row = idx >> 3, c = idx & 7;
    int ks = n * BSZ - BSZ + row;
    uint4 v = make_uint4(0u, 0u, 0u, 0u);
    if (ks >= 0 && ks < SEQ) v = *(const uint4*)(kbh + (size_t)ks * HDIM + c * 8);
    stfrag(smem + K_OFF, row, 128, c, v);
  }
  for (int idx = tid; idx < 384 * 8; idx += 512) {
    int row = idx >> 3, c = idx & 7;
    uint4 v = *(const uint4*)(pqh + row * HDIM + c * 8);
    stfrag(smem + PQ_OFF, row, 128, c, v);
  }
  __syncthreads();

  // ---- phase 4: p2c, 12 subtiles; Tl double-buffered (slot s&1) ->
  //      only ONE barrier per subtile (trailing barrier removed).
#pragma unroll
  for (int s = 0; s < 12; ++s) {
    unsigned short* Tl =
        (unsigned short*)(smem + ((s & 1) ? Q_OFF : T_OFF));
    const int lo = iLUT[352 - 32 * s];
    const int hi = iLUT[510 - 32 * s];
    const int ntiles = ((hi - lo + 1) + 15) >> 4;
    for (int tl = wave; tl < 2 * ntiles; tl += 8) {
      int mt = tl & 1, ntl = tl >> 1;
      bf16x8 a0 = ldfrag128(smem, K_OFF, 32 * s + 16 * mt + l15, 128, 0, g);
      bf16x8 a1 = ldfrag128(smem, K_OFF, 32 * s + 16 * mt + l15, 128, 1, g);
      int prow = lo + 16 * ntl + l15;
      prow = prow > 383 ? 383 : prow;
      bf16x8 b0 = ldfrag128(smem, PQ_OFF, prow, 128, 0, g);
      bf16x8 b1 = ldfrag128(smem, PQ_OFF, prow, 128, 1, g);
      f32x4 c = {0.f, 0.f, 0.f, 0.f};
      c = MFMA16(a0, b0, c);
      c = MFMA16(a1, b1, c);
#pragma unroll
      for (int r = 0; r < 4; ++r)
        Tl[(16 * mt + 4 * g + r) * TLS + 16 * ntl + l15] = f2bf(c[r]);
    }
    __syncthreads();  // Tl[s&1] ready; next iteration writes the OTHER slot
    {
      const int dbase2 = qs + l15 - 32 * s - 4 * g + 383;
#pragma unroll
      for (int tt = 0; tt < 2; ++tt) {
#pragma unroll
        for (int r = 0; r < 4; ++r) {
          int idx = iLUT[dbase2 - 16 * tt - r];
          acc[2 * s + tt][r] += bf2f(Tl[(16 * tt + 4 * g + r) * TLS + idx - lo]);
        }
      }
    }
  }

  // ---- phase 5: QK^T accumulate (A = K rows, B = Q^T)
  __syncthreads();  // last Tl gather complete before reuse checks; K stable
  __builtin_amdgcn_s_setprio(1);
#pragma unroll
  for (int t = 0; t < 24; ++t) {
    bf16x8 a0 = ldfrag128(smem, K_OFF, 16 * t + l15, 128, 0, g);
    bf16x8 a1 = ldfrag128(smem, K_OFF, 16 * t + l15, 128, 1, g);
    acc[t] = MFMA16(a0, qf0, acc[t]);
    acc[t] = MFMA16(a1, qf1, acc[t]);
  }
  __builtin_amdgcn_s_setprio(0);
  __syncthreads();  // posq region dead; about to become Vt

  // ---- phase 6: stage Vt transposed from vws [s][d]; packed b32 writes.
  for (int idx = tid; idx < 1536; idx += 512) {
    int u2 = idx % 192;
    int dg = idx / 192;
    int s0v = 2 * u2;
    int ks0 = n * BSZ - BSZ + s0v;
    uint4 va = make_uint4(0u, 0u, 0u, 0u);
    uint4 vb = make_uint4(0u, 0u, 0u, 0u);
    if (ks0 >= 0 && ks0 < SEQ)
      va = *(const uint4*)(vbh + (size_t)ks0 * HDIM + dg * 8);
    if (ks0 + 1 >= 0 && ks0 + 1 < SEQ)
      vb = *(const uint4*)(vbh + (size_t)(ks0 + 1) * HDIM + dg * 8);
    union { uint4 q; unsigned short u[8]; } wa, wb;
    wa.q = va; wb.q = vb;
    const int nc = 2 * vperm(s0v);
#pragma unroll
    for (int j = 0; j < 8; ++j) {
      int d = dg * 8 + j;
      unsigned int pk = (unsigned int)wa.u[j] | ((unsigned int)wb.u[j] << 16);
      *(unsigned int*)(smem + VT_OFF + d * 768 + (nc ^ ((d & 7) << 4))) = pk;
    }
  }

  // ---- phase 7: softmax (in-register; q = qs + l15 fixed per lane)
  float m = -1e30f;
#pragma unroll
  for (int t = 0; t < 24; ++t)
#pragma unroll
    for (int r = 0; r < 4; ++r) m = fmaxf(m, acc[t][r]);
  m = fmaxf(m, __shfl_xor(m, 16));
  m = fmaxf(m, __shfl_xor(m, 32));
  float sum = 0.f;
#pragma unroll
  for (int t = 0; t < 24; ++t)
#pragma unroll
    for (int r = 0; r < 4; ++r) {
      float p = exp2f((acc[t][r] - m) * 0.10411790f);  // /sqrt(192) * log2e
      acc[t][r] = p;
      sum += p;
    }
  sum += __shfl_xor(sum, 16);
  sum += __shfl_xor(sum, 32);
  float inv = 1.0f / sum;

  bf16x8 pa[12];
#pragma unroll
  for (int kt = 0; kt < 12; ++kt) {
    union { bf16x8 v; unsigned short u[8]; } w;
#pragma unroll
    for (int j = 0; j < 4; ++j) w.u[j] = f2bf(acc[2 * kt][j] * inv);
#pragma unroll
    for (int j = 0; j < 4; ++j) w.u[4 + j] = f2bf(acc[2 * kt + 1][j] * inv);
    pa[kt] = w.v;
  }
  __syncthreads();  // Vt staged

  // ---- phase 8: PV, write ctx bf16
  unsigned short* ctxg = ctx + ((size_t)b * SEQ + n * BSZ) * HID + h * HDIM;
  __builtin_amdgcn_s_setprio(1);
#pragma unroll
  for (int nt = 0; nt < 4; ++nt) {
    f32x4 o = {0.f, 0.f, 0.f, 0.f};
#pragma unroll
    for (int kt = 0; kt < 12; ++kt) {
      bf16x8 bv = ldfrag128(smem, VT_OFF, 16 * nt + l15, 768, kt, g);
      o = MFMA16(pa[kt], bv, o);
    }
#pragma unroll
    for (int r = 0; r < 4; ++r) {
      size_t off = (size_t)(qs + 4 * g + r) * HID + 16 * nt + l15;
      ctxg[off] = f2bf(o[r]);
    }
  }
  __builtin_amdgcn_s_setprio(0);
}

// ---------------------------------------------------------------------------
// Fused out-projection + bias + residual + LayerNorm.
__global__ __launch_bounds__(512) void out_ln(
    const unsigned short* __restrict__ ctx, const unsigned short* __restrict__ WoT,
    const float* __restrict__ bo, const float* __restrict__ hidden,
    const float* __restrict__ lns, const float* __restrict__ lnb,
    float* __restrict__ out) {
  extern __shared__ char smem[];
  unsigned short* Au = (unsigned short*)(smem + OL_AU);
  unsigned short* Bu = (unsigned short*)(smem + OL_BU);
  float* red1 = (float*)(smem + OL_R1);
  float* red2 = (float*)(smem + OL_R2);
  float* muA = (float*)(smem + OL_MU);
  float* rsA = (float*)(smem + OL_RS);

  const int t = threadIdx.x;
  const int lane = t & 63;
  const int l15 = lane & 15, g = lane >> 4;
  const int w = t >> 6;
  const int m0 = blockIdx.x * 64;

  f32x4 acc[4][6];
#pragma unroll
  for (int mt = 0; mt < 4; ++mt)
#pragma unroll
    for (int nt = 0; nt < 6; ++nt) acc[mt][nt] = (f32x4){0.f, 0.f, 0.f, 0.f};

  for (int k0 = 0; k0 < HID; k0 += 32) {
    if (t < 256) {
      int r = t >> 2, c = t & 3;
      uint4 v = *(const uint4*)(ctx + (size_t)(m0 + r) * HID + k0 + c * 8);
      *(uint4*)(Au + r * 40 + c * 8) = v;
    }
#pragma unroll
    for (int i = 0; i < 6; ++i) {
      int idx = t + i * 512;
      int nrow = idx >> 2, c = idx & 3;
      uint4 v = *(const uint4*)(WoT + (size_t)nrow * HID + k0 + c * 8);
      *(uint4*)(Bu + nrow * 40 + c * 8) = v;
    }
    __syncthreads();
    bf16x8 af[4];
#pragma unroll
    for (int mt = 0; mt < 4; ++mt) af[mt] = olfrag(Au, mt * 16 + l15, g);
#pragma unroll
    for (int nt = 0; nt < 6; ++nt) {
      bf16x8 bf = olfrag(Bu, w * 96 + nt * 16 + l15, g);
#pragma unroll
      for (int mt = 0; mt < 4; ++mt)
        acc[mt][nt] = MFMA16(af[mt], bf, acc[mt][nt]);
    }
    __syncthreads();
  }

  float psum[4][4] = {};
  float psq[4][4] = {};
#pragma unroll
  for (int nt = 0; nt < 6; ++nt) {
    int gn = w * 96 + nt * 16 + l15;
    float bval = bo[gn];
#pragma unroll
    for (int mt = 0; mt < 4; ++mt) {
#pragma unroll
      for (int r = 0; r < 4; ++r) {
        int gm = m0 + mt * 16 + 4 * g + r;
        float v = acc[mt][nt][r] + bval + hidden[(size_t)gm * HID + gn];
        acc[mt][nt][r] = v;
        psum[mt][r] += v;
        psq[mt][r] += v * v;
      }
    }
  }
#pragma unroll
  for (int o = 1; o < 16; o <<= 1) {
#pragma unroll
    for (int mt = 0; mt < 4; ++mt)
#pragma unroll
      for (int r = 0; r < 4; ++r) {
        psum[mt][r] += __shfl_xor(psum[mt][r], o);
        psq[mt][r] += __shfl_xor(psq[mt][r], o);
      }
  }
  if (l15 == 0) {
#pragma unroll
    for (int mt = 0; mt < 4; ++mt)
#pragma unroll
      for (int r = 0; r < 4; ++r) {
        red1[(mt * 16 + 4 * g + r) * 8 + w] = psum[mt][r];
        red2[(mt * 16 + 4 * g + r) * 8 + w] = psq[mt][r];
      }
  }
  __syncthreads();
  if (t < 64) {
    float s = 0.f, s2 = 0.f;
#pragma unroll
    for (int i = 0; i < 8; ++i) {
      s += red1[t * 8 + i];
      s2 += red2[t * 8 + i];
    }
    float mu = s * (1.0f / 768.0f);
    float var = s2 * (1.0f / 768.0f) - mu * mu;
    muA[t] = mu;
    rsA[t] = 1.0f / sqrtf(var + 1e-7f);
  }
  __syncthreads();
#pragma unroll
  for (int nt = 0; nt < 6; ++nt) {
    int gn = w * 96 + nt * 16 + l15;
    float sc = lns[gn], bi = lnb[gn];
#pragma unroll
    for (int mt = 0; mt < 4; ++mt) {
#pragma unroll
      for (int r = 0; r < 4; ++r) {
        int lm = mt * 16 + 4 * g + r;
        float v = (acc[mt][nt][r] - muA[lm]) * rsA[lm] * sc + bi;
        out[(size_t)(m0 + lm) * HID + gn] = v;
      }
    }
  }
}

extern "C" void kernel_launch(void* const* d_in, const int* in_sizes, int n_in,
                              void* d_out, int out_size, void* d_ws,
                              size_t ws_size, hipStream_t stream) {
  (void)in_sizes; (void)n_in; (void)out_size; (void)ws_size;
  const float* hidden = (const float*)d_in[0];
  const float* relpos = (const float*)d_in[1];
  const float* Wq = (const float*)d_in[2];
  const float* bq = (const float*)d_in[3];
  const float* Wk = (const float*)d_in[4];
  const float* bk = (const float*)d_in[5];
  const float* Wv = (const float*)d_in[6];
  const float* bv = (const float*)d_in[7];
  const float* Wo = (const float*)d_in[8];
  const float* bo = (const float*)d_in[9];
  const float* lns = (const float*)d_in[10];
  const float* lnb = (const float*)d_in[11];
  float* out = (float*)d_out;

  // Workspace (ushort units), total 207,618,048 B == proven footprint.
  unsigned short* ws = (unsigned short*)d_ws;
  const size_t QE = (size_t)48 * SEQ * HDIM;   // 25,165,824
  const size_t PE = (size_t)NHEADS * PBUCK * HDIM;  // 393,216
  unsigned short* qws = ws;
  unsigned short* kws = qws + QE;
  unsigned short* vws = kws + QE;
  unsigned short* ctx = vws + QE;
  unsigned short* hbf = ctx;                   // alias: dead before attn writes
  unsigned short* posq = ctx + QE;
  unsigned short* posk = posq + PE;
  unsigned short* Wt4 = posk + PE;             // 4 x 589,824
  unsigned short* WoT = Wt4 + (size_t)3 * HID * HID;

  static bool attrib_set = false;
  if (!attrib_set) {
    hipFuncSetAttribute((const void*)attn_kernel,
                        hipFuncAttributeMaxDynamicSharedMemorySize, SMEM_ATTN);
    hipFuncSetAttribute((const void*)out_ln,
                        hipFuncAttributeMaxDynamicSharedMemorySize, SMEM_OL);
    attrib_set = true;
  }

  hbf_conv<<<12288, 256, 0, stream>>>(hidden, hbf);
  conv_wt<<<dim3(12, 12, 4), 256, 0, stream>>>(Wq, Wk, Wv, Wo, Wt4);
  pos_gemm<<<dim3(8, 24), 256, 0, stream>>>(relpos, Wq, Wk, bq, bk, posq, posk);
  qkv_mfma<<<4608, 256, 0, stream>>>(hbf, Wt4, bq, bk, bv, qws, kws, vws);
  attn_kernel<<<3072, 512, SMEM_ATTN, stream>>>(qws, kws, vws, posq, posk, ctx);
  out_ln<<<512, 512, SMEM_OL, stream>>>(ctx, WoT, bo, hidden, lns, lnb, out);
}